// Round 5
// baseline (206.658 us; speedup 1.0000x reference)
//
#include <hip/hip_runtime.h>
#include <hip/hip_bf16.h>

typedef __bf16 bf16x8 __attribute__((ext_vector_type(8)));
typedef __bf16 bf16x4 __attribute__((ext_vector_type(4)));
typedef float  f32x4  __attribute__((ext_vector_type(4)));

#define H 768
#define LSEQ 2048
#define BATCH 32
#define MROWS (BATCH*LSEQ)   /* 65536 */
#define NT 3                 /* 768/256 n-tiles */
#define W2S 2304             /* W2 row stride (3H) */

__device__ __forceinline__ void gload_lds16(const void* g, void* l){
  __builtin_amdgcn_global_load_lds((const __attribute__((address_space(1))) void*)g,
                                   (__attribute__((address_space(3))) void*)l, 16, 0, 0);
}

// Phase barrier pair (template m201): open-barrier + lgkm0 before MFMA, close after.
#define PBAR() do{ __builtin_amdgcn_sched_barrier(0); __builtin_amdgcn_s_barrier(); \
  asm volatile("s_waitcnt lgkmcnt(0)" ::: "memory"); __builtin_amdgcn_sched_barrier(0);}while(0)
#define CBAR() do{ __builtin_amdgcn_sched_barrier(0); __builtin_amdgcn_s_barrier(); \
  __builtin_amdgcn_sched_barrier(0);}while(0)

// ---- convert W2c = W2[:, 2H:3H] to bf16 (row-major [g][h], h contiguous) ----
__global__ void w2c_cvt_k(const float* __restrict__ W2, __bf16* __restrict__ w2cb){
  int i4 = blockIdx.x*256 + threadIdx.x;     // 147456 float4s total
  int g  = i4 / 192;
  int hc = (i4 % 192) * 4;
  f32x4 v = *(const f32x4*)(W2 + (size_t)g*W2S + 1536 + hc);
  bf16x4 o; o[0]=(__bf16)v[0]; o[1]=(__bf16)v[1]; o[2]=(__bf16)v[2]; o[3]=(__bf16)v[3];
  *(bf16x4*)(w2cb + (size_t)g*H + hc) = o;
}

// ---- bias_bh[b][g] = in1[b]·W2a[g] + in2[b]·W2b[g] + b2[g] ----
__global__ void bias_k(const float* __restrict__ in1, const float* __restrict__ in2,
                       const float* __restrict__ W2, const float* __restrict__ b2,
                       float* __restrict__ bias){
  int b = blockIdx.y;
  int g = blockIdx.x*64 + (threadIdx.x & 63);
  int q = threadIdx.x >> 6;                  // h-quarter
  const float* wa = W2 + (size_t)g*W2S + q*192;
  const float* wb = wa + H;
  const float* x1 = in1 + b*H + q*192;
  const float* x2 = in2 + b*H + q*192;
  float acc = 0.f;
  #pragma unroll 8
  for (int h=0; h<192; h+=4){
    f32x4 a4 = *(const f32x4*)(wa+h);
    f32x4 c4 = *(const f32x4*)(x1+h);
    f32x4 b4 = *(const f32x4*)(wb+h);
    f32x4 d4 = *(const f32x4*)(x2+h);
    acc += a4[0]*c4[0]+a4[1]*c4[1]+a4[2]*c4[2]+a4[3]*c4[3];
    acc += b4[0]*d4[0]+b4[1]*d4[1]+b4[2]*d4[2]+b4[3]*d4[3];
  }
  __shared__ float sm[4][64];
  sm[q][threadIdx.x&63] = acc;
  __syncthreads();
  if (q==0){
    float r = sm[0][threadIdx.x]+sm[1][threadIdx.x]+sm[2][threadIdx.x]+sm[3][threadIdx.x] + b2[g];
    bias[(size_t)b*H + g] = r;
  }
}

// ---- fused: S = text·W2c^T (bf16 MFMA), att_part = sum_g tanh(S+bias)·W1 ----
// 8-phase template port (m201 lineage): 256x256 tile, BK=32, 8 waves (2Mx4N),
// 512 threads, wave-tile 128x64, 1 block/CU. Per K-step 4 phases:
// {frag ds_reads || one stage cluster; barrier; lgkm0; prio1 8xMFMA prio0; barrier}.
// Counted waits: A-reg write waits vmcnt(2) (leaves B DMA in flight); single
// vmcnt(0) per K-step at P4-end (B gloads, issued 2 phases earlier).
// Granule XOR swizzle g^=(row>>1)&3 on both tiles (R3/R4-verified 0 conflicts).
__global__ __launch_bounds__(512,2) void fused_gemm_att_k(
    const float* __restrict__ text, const __bf16* __restrict__ w2cb,
    const float* __restrict__ bias, const float* __restrict__ W1,
    float* __restrict__ attp)
{
  __shared__ __align__(16) __bf16 a_lds[2][256*32];  // 32 KiB
  __shared__ __align__(16) __bf16 b_lds[2][256*32];  // 32 KiB
  __shared__ float att_lds[4][256];                  // 4 KiB

  int bid = blockIdx.x;                 // 768 = 256 m-tiles * 3 n-tiles
  int lin = (bid & 7)*96 + (bid >> 3);  // bijective XCD chunking (768 % 8 == 0)
  int mt  = lin / 3;
  int nt  = lin % 3;
  int m0  = mt << 8;                    // 256 rows/tile
  int b   = m0 >> 11;                   // 2048 rows/batch
  int t = threadIdx.x, lane = t & 63, wid = t >> 6;
  int wm = wid >> 2, wn = wid & 3;      // 2 x 4 waves

  const float*  atile = text + (size_t)m0*H;
  const __bf16* btile = w2cb + (size_t)(nt*256)*H;

  f32x4 acc[8][4];
  #pragma unroll
  for (int mi=0;mi<8;++mi)
    #pragma unroll
    for (int ni=0;ni<4;++ni) acc[mi][ni] = (f32x4){0.f,0.f,0.f,0.f};

  // ---- A staging: thread t loads 16 f32 (row t>>1, col-half t&1), cvt, 2x b128 write
  int arow = t>>1, acg = t&1;
  const float* aptr = atile + (size_t)arow*H + acg*16;
  int aswz = (arow>>1)&3;
  int aw0 = arow*32 + (((2*acg  )^aswz)*8);
  int aw1 = arow*32 + (((2*acg+1)^aswz)*8);
  f32x4 aReg[4];

  // ---- B staging: 16 KB = 16 wave-slots of 1 KiB; 2 gload_lds per wave
  int slot0 = wid*2, slot1 = wid*2+1;
  int bn0 = slot0*16 + (lane>>2), bn1 = slot1*16 + (lane>>2);
  const __bf16* bsrc0 = btile + (size_t)bn0*H + (((lane&3)^((bn0>>1)&3))*8);
  const __bf16* bsrc1 = btile + (size_t)bn1*H + (((lane&3)^((bn1>>1)&3))*8);

  auto loadA = [&](int kk){
    #pragma unroll
    for (int j=0;j<4;++j) aReg[j] = *(const f32x4*)(aptr + kk*32 + j*4);
  };
  auto writeA = [&](int bf){
    bf16x8 lo, hi;
    lo[0]=(__bf16)aReg[0][0]; lo[1]=(__bf16)aReg[0][1]; lo[2]=(__bf16)aReg[0][2]; lo[3]=(__bf16)aReg[0][3];
    lo[4]=(__bf16)aReg[1][0]; lo[5]=(__bf16)aReg[1][1]; lo[6]=(__bf16)aReg[1][2]; lo[7]=(__bf16)aReg[1][3];
    hi[0]=(__bf16)aReg[2][0]; hi[1]=(__bf16)aReg[2][1]; hi[2]=(__bf16)aReg[2][2]; hi[3]=(__bf16)aReg[2][3];
    hi[4]=(__bf16)aReg[3][0]; hi[5]=(__bf16)aReg[3][1]; hi[6]=(__bf16)aReg[3][2]; hi[7]=(__bf16)aReg[3][3];
    *(bf16x8*)&a_lds[bf][aw0] = lo;
    *(bf16x8*)&a_lds[bf][aw1] = hi;
  };
  auto stageB = [&](int bf, int kk){
    gload_lds16(bsrc0 + kk*32, &b_lds[bf][slot0*512]);
    gload_lds16(bsrc1 + kk*32, &b_lds[bf][slot1*512]);
  };

  int fr = lane&15, fc = lane>>4;
  auto rdA = [&](int bf, int mh, bf16x8* af){
    #pragma unroll
    for (int mi=0;mi<4;++mi){
      int row = wm*128 + mh*64 + mi*16 + fr;
      af[mi] = *(const bf16x8*)&a_lds[bf][row*32 + ((fc^((row>>1)&3))*8)];
    }
  };
  auto rdB = [&](int bf, int nh, bf16x8* bq){
    #pragma unroll
    for (int j=0;j<2;++j){
      int n = wn*64 + nh*32 + j*16 + fr;
      bq[j] = *(const bf16x8*)&b_lds[bf][n*32 + ((fc^((n>>1)&3))*8)];
    }
  };
  auto mfma8 = [&](int mh, int nh, bf16x8* af, bf16x8* bq){
    __builtin_amdgcn_s_setprio(1);
    #pragma unroll
    for (int mi=0;mi<4;++mi)
      #pragma unroll
      for (int j=0;j<2;++j)
        acc[mh*4+mi][nh*2+j] =
          __builtin_amdgcn_mfma_f32_16x16x32_bf16(af[mi], bq[j], acc[mh*4+mi][nh*2+j], 0,0,0);
    __builtin_amdgcn_s_setprio(0);
  };

  // ---- prologue: stage K-step 0 into buf 0
  loadA(0);
  stageB(0, 0);
  writeA(0);                       // compiler waits the A loads (vmcnt)
  asm volatile("s_waitcnt vmcnt(0) lgkmcnt(0)" ::: "memory");
  __builtin_amdgcn_s_barrier();

  // ---- K loop: 24 steps, 4 phases each. Quadrants (0,0),(0,1),(1,1),(1,0).
  #pragma unroll 2
  for (int s=0; s<24; ++s){
    int p = s&1, q = p^1;
    bf16x8 a0[4], a1[4], b0[2], b1[2];
    // P1: reads A0,B0 | issue A global loads (s+1)
    rdA(p,0,a0); rdB(p,0,b0);
    if (s<23) loadA(s+1);
    PBAR(); mfma8(0,0,a0,b0); CBAR();
    // P2: reads B1 (A0 resident) | issue B gload_lds (s+1)
    rdB(p,1,b1);
    if (s<23) stageB(q, s+1);
    PBAR(); mfma8(0,1,a0,b1); CBAR();
    // P3: reads A1 (B1 resident) | A cvt+ds_write (waits vmcnt(2): A regs, leaves B)
    rdA(p,1,a1);
    if (s<23) writeA(q);
    PBAR(); mfma8(1,1,a1,b1); CBAR();
    // P4: re-read B0 (A1 resident) | drain B DMA at end (only vmem wait of the step)
    rdB(p,0,b0);
    PBAR(); mfma8(1,0,a1,b0);
    if (s<23) asm volatile("s_waitcnt vmcnt(0)" ::: "memory");
    CBAR();
  }

  // ---- epilogue: lane n-col = nt*256 + wn*64 + ni*16 + fr
  float bb[4], ww[4];
  int gb = nt*256 + wn*64 + fr;
  #pragma unroll
  for (int ni=0;ni<4;++ni){ bb[ni]=bias[(size_t)b*H + gb + ni*16]; ww[ni]=W1[gb + ni*16]; }

  float av[32];
  #pragma unroll
  for (int mi=0;mi<8;++mi)
    #pragma unroll
    for (int r=0;r<4;++r){
      float s = 0.f;
      #pragma unroll
      for (int ni=0;ni<4;++ni){
        float x = acc[mi][ni][r] + bb[ni];
        float e = __expf(2.0f*x);            // tanh(x) = (e^2x-1)/(e^2x+1)
        s += ww[ni] * ((e-1.0f)*__builtin_amdgcn_rcpf(e+1.0f));
      }
      av[mi*4+r] = s;
    }
  #pragma unroll
  for (int off=1; off<16; off<<=1)
    #pragma unroll
    for (int i=0;i<32;++i) av[i] += __shfl_xor(av[i], off);

  if (fr==0){
    #pragma unroll
    for (int mi=0;mi<8;++mi)
      #pragma unroll
      for (int r=0;r<4;++r)
        att_lds[wn][wm*128 + mi*16 + fc*4 + r] = av[mi*4+r];
  }
  __syncthreads();
  if (t < 256)
    attp[(size_t)nt*MROWS + m0 + t] =
      att_lds[0][t] + att_lds[1][t] + att_lds[2][t] + att_lds[3][t];
}

// ---- softmax over L per batch row (sums the 3 n-tile partials) ----
__global__ void softmax_k(const float* __restrict__ attp, const float* __restrict__ tmask,
                          const float* __restrict__ b1, float* __restrict__ att){
  int b = blockIdx.x, t = threadIdx.x;
  int lane = t & 63, wv = t >> 6;
  __shared__ float sl[LSEQ];
  __shared__ float red[4];
  float b1v = b1[0];
  float lmax = -3.0e38f;
  for (int i=t; i<LSEQ; i+=256){
    float v = b1v;
    #pragma unroll
    for (int p=0;p<NT;++p) v += attp[(size_t)p*MROWS + b*LSEQ + i];
    v += (1.0f - tmask[b*LSEQ+i]) * -1.0e20f;
    sl[i] = v;
    lmax = fmaxf(lmax, v);
  }
  #pragma unroll
  for (int off=32; off>=1; off>>=1) lmax = fmaxf(lmax, __shfl_xor(lmax, off));
  if (lane==0) red[wv] = lmax;
  __syncthreads();
  float mx = fmaxf(fmaxf(red[0],red[1]), fmaxf(red[2],red[3]));
  __syncthreads();
  float lsum = 0.f;
  for (int i=t; i<LSEQ; i+=256){
    float e = __expf(sl[i]-mx);
    sl[i] = e;
    lsum += e;
  }
  #pragma unroll
  for (int off=32; off>=1; off>>=1) lsum += __shfl_xor(lsum, off);
  if (lane==0) red[wv] = lsum;
  __syncthreads();
  float inv = 1.0f/(red[0]+red[1]+red[2]+red[3]);
  for (int i=t; i<LSEQ; i+=256) att[(size_t)b*LSEQ+i] = sl[i]*inv;
}

// ---- context partials: 64-row chunks, block=192 threads (one float4 per thread) ----
__global__ void ctxpart_k(const float* __restrict__ text, const float* __restrict__ att,
                          float* __restrict__ ctxp){
  int chunk = blockIdx.x, b = blockIdx.y, t = threadIdx.x;
  const float* tp = text + ((size_t)(b*LSEQ + chunk*64))*H + 4*t;
  const float* ap = att + (size_t)b*LSEQ + chunk*64;
  f32x4 acc = {0.f,0.f,0.f,0.f};
  #pragma unroll 4
  for (int l=0;l<64;++l){
    float a = ap[l];
    f32x4 v = *(const f32x4*)(tp + (size_t)l*H);
    acc[0] += a*v[0]; acc[1] += a*v[1]; acc[2] += a*v[2]; acc[3] += a*v[3];
  }
  *(f32x4*)(ctxp + ((size_t)(b*32+chunk))*H + 4*t) = acc;
}

__global__ void ctxred_k(const float* __restrict__ ctxp, float* __restrict__ out){
  int b = blockIdx.x, h = threadIdx.x;   // block 768
  float s = 0.f;
  #pragma unroll 8
  for (int c=0;c<32;++c) s += ctxp[((size_t)(b*32+c))*H + h];
  out[(size_t)b*H + h] = s;
}

extern "C" void kernel_launch(void* const* d_in, const int* in_sizes, int n_in,
                              void* d_out, int out_size, void* d_ws, size_t ws_size,
                              hipStream_t stream){
  (void)in_sizes; (void)n_in; (void)out_size; (void)ws_size;
  const float* in1   = (const float*)d_in[0];
  const float* in2   = (const float*)d_in[1];
  const float* text  = (const float*)d_in[2];
  const float* tmask = (const float*)d_in[3];
  const float* W2    = (const float*)d_in[4];
  const float* b2    = (const float*)d_in[5];
  const float* W1    = (const float*)d_in[6];
  const float* b1    = (const float*)d_in[7];
  float* out = (float*)d_out;              // [0,24576): context, [24576,90112): att
  char*  ws  = (char*)d_ws;
  // ws layout (bytes): w2c bf16 1179648 | bias 98304 | attp 786432 | ctxp 3145728
  __bf16* w2cb = (__bf16*)(ws);
  float* biasb = (float*)(ws + 1179648);
  float* attp  = (float*)(ws + 1277952);
  float* ctxp  = (float*)(ws + 2850816);
  float* att_out = out + BATCH*H;

  w2c_cvt_k      <<<dim3(576),   dim3(256), 0, stream>>>(W2, w2cb);
  bias_k         <<<dim3(12,32), dim3(256), 0, stream>>>(in1, in2, W2, b2, biasb);
  fused_gemm_att_k<<<dim3(768),  dim3(512), 0, stream>>>(text, w2cb, biasb, W1, attp);
  softmax_k      <<<dim3(32),    dim3(256), 0, stream>>>(attp, tmask, b1, att_out);
  ctxpart_k      <<<dim3(32,32), dim3(192), 0, stream>>>(text, att_out, ctxp);
  ctxred_k       <<<dim3(32),    dim3(768), 0, stream>>>(ctxp, out);
}